// Round 4
// baseline (1345.993 us; speedup 1.0000x reference)
//
#include <hip/hip_runtime.h>
#include <hip/hip_bf16.h>

typedef __hip_bfloat16 bf16;

#define Bn 4
#define Dm 512
#define Hh 8
#define V3 3
#define Lq 1024
#define NM (Bn*Hh*V3)   // 96 attention maps

__device__ __forceinline__ unsigned short f2bf(float x) {
    bf16 h = __float2bfloat16(x);
    return *reinterpret_cast<unsigned short*>(&h);
}
__device__ __forceinline__ float bfbits2f(unsigned short u) {
    return __uint_as_float((unsigned)u << 16);
}

constexpr float SCALE = 0.57735026919f; // 1/sqrt(3)

// ---------------------------------------------------------------------------
// Kernel 1: ALL THREE projections in one launch.
// Y[l,e] = sum_d W[e,d] * x[b,d,v,l] per (b,v).
// pid 0 (Q), 1 (K): fp32 transposed out  [(m*64+dd)*1024 + l]
// pid 2 (V):        bf16 natural out     [(m*1024+l)*64 + dd]
// Tile: 256 l x 64 e, K-step 32, acc 16x4/thread, 40 KiB LDS, block 256.
// grid: 1152 blocks (4 x-l, 8 y-e, 36 z=(pid,b,v)), chunk-swizzled (1152=8*144).
// Inner loop: 64 FMA : 5 ds_read_b128, conflict-free via XOR-swizzled W.
// ---------------------------------------------------------------------------
__global__ __launch_bounds__(256, 4) void proj_all_kernel(
    const float* __restrict__ xq, const float* __restrict__ xk,
    const float* __restrict__ xv,
    const float* __restrict__ Wq, const float* __restrict__ Wk,
    const float* __restrict__ Wv,
    float* __restrict__ Qt, float* __restrict__ Kt, bf16* __restrict__ Vh)
{
    __shared__ float4 Xf4[32 * 64];   // [d][l] natural, 32 KiB
    __shared__ float4 Wf4[32 * 16];   // [d][e] transposed, swizzled, 8 KiB
    float* Ws = reinterpret_cast<float*>(Wf4);

    const int fid = (blockIdx.z * gridDim.y + blockIdx.y) * gridDim.x + blockIdx.x;
    const int nid = (fid & 7) * 144 + (fid >> 3);
    const int x_  = nid & 3;          // l-block (4)
    const int y_  = (nid >> 2) & 7;   // e-block (8)
    const int zz  = nid >> 5;         // 0..35
    const int pid = zz / 12;          // 0=Q 1=K 2=V
    const int pl  = zz % 12;
    const int b   = pl / V3;
    const int v   = pl % V3;

    const float* xsrc = (pid == 0) ? xq : (pid == 1) ? xk : xv;
    const float* W    = (pid == 0) ? Wq : (pid == 1) ? Wk : Wv;

    const int l0 = x_ * 256;
    const int e0 = y_ * 64;
    const int h  = y_;
    const int m  = (b * Hh + h) * V3 + v;

    const int tid = threadIdx.x;
    const int txl = tid & 15;     // owns l = l0 + u*64 + txl*4 + ii, u=0..3
    const int tye = tid >> 4;     // owns e = e0 + tye*4 + j

    float acc[16][4] = {};

    for (int ph = 0; ph < 16; ++ph) {
        const int d0 = ph * 32;
        __syncthreads();
        // stage X natural [d][l]: 2048 f4, coalesced
        #pragma unroll
        for (int q2 = 0; q2 < 8; ++q2) {
            int idx = tid + q2 * 256;
            int r = idx >> 6, g = idx & 63;
            Xf4[r * 64 + g] = *reinterpret_cast<const float4*>(
                xsrc + ((size_t)(b * Dm + d0 + r) * V3 + v) * Lq + l0 + g * 4);
        }
        // stage W transposed [d][e], XOR-swizzled f4 groups (scalar scatter)
        #pragma unroll
        for (int q2 = 0; q2 < 2; ++q2) {
            int idx = tid + q2 * 256;
            int erow = idx >> 3, g = idx & 7;
            float4 wv4 = *reinterpret_cast<const float4*>(
                W + (size_t)(e0 + erow) * Dm + d0 + g * 4);
            float wz[4] = {wv4.x, wv4.y, wv4.z, wv4.w};
            #pragma unroll
            for (int di = 0; di < 4; ++di) {
                int d = g * 4 + di;
                Ws[d * 64 + (((erow >> 2) ^ (d & 15)) << 2) + (erow & 3)] = wz[di];
            }
        }
        __syncthreads();

        #pragma unroll 4
        for (int kk = 0; kk < 32; ++kk) {
            float4 b4 = Wf4[kk * 16 + (tye ^ (kk & 15))];
            float bb[4] = {b4.x, b4.y, b4.z, b4.w};
            float a[16];
            #pragma unroll
            for (int u = 0; u < 4; ++u) {
                float4 a4 = Xf4[kk * 64 + u * 16 + txl];
                a[u*4+0] = a4.x; a[u*4+1] = a4.y; a[u*4+2] = a4.z; a[u*4+3] = a4.w;
            }
            #pragma unroll
            for (int i = 0; i < 16; ++i)
                #pragma unroll
                for (int j = 0; j < 4; ++j)
                    acc[i][j] = fmaf(a[i], bb[j], acc[i][j]);
        }
    }

    if (pid < 2) {
        float* outT = (pid == 0) ? Qt : Kt;
        #pragma unroll
        for (int j = 0; j < 4; ++j) {
            #pragma unroll
            for (int u = 0; u < 4; ++u) {
                float4 f4 = make_float4(acc[u*4+0][j], acc[u*4+1][j],
                                        acc[u*4+2][j], acc[u*4+3][j]);
                *reinterpret_cast<float4*>(
                    outT + (((size_t)(m * 64 + tye * 4 + j)) << 10)
                         + l0 + u * 64 + txl * 4) = f4;
            }
        }
    } else {
        #pragma unroll
        for (int i = 0; i < 16; ++i) {
            int l = l0 + (i >> 2) * 64 + txl * 4 + (i & 3);
            union { unsigned short u[4]; uint2 v2; } pk;
            #pragma unroll
            for (int j = 0; j < 4; ++j) pk.u[j] = f2bf(acc[i][j]);
            *reinterpret_cast<uint2*>(
                Vh + ((size_t)m * Lq + l) * 64 + tye * 4) = pk.v2;
        }
    }
}

// ---------------------------------------------------------------------------
// Kernel 2 (fused flash, no-max softmax, P-overwrites-K, adaptive p-buffer):
//   per 64-row stripe: QK^T -> p=exp(s*scale) -> p to (bf16 ws | fp32 out) ->
//   P~ into K's LDS -> O += P~.V -> tail: O*inv write + coalesced normalize.
// grid: 1536 blocks (XCD-chunk swizzled), block 256. LDS 48 KiB (3 blk/CU).
// ---------------------------------------------------------------------------
__global__ __launch_bounds__(256) void fused_attn_kernel(
    const float* __restrict__ Qt, const float* __restrict__ Kt,
    const bf16* __restrict__ Vh, float* __restrict__ attn_out,
    bf16* __restrict__ Ot, unsigned short* __restrict__ pws, int usews)
{
    __shared__ float4 smem4[3 * 1024];   // 48 KiB
    float4* Qf4 = smem4;                 // [dd][l]
    float4* Kf4 = smem4 + 1024;          // [dd][s]  (becomes P~ [s][l] after QK)
    float4* Vf4 = smem4 + 2048;          // [s][dd]
    float4* Pf4 = Kf4;
    float* Linv = reinterpret_cast<float*>(smem4);  // tail alias (Q region)

    const int fid = blockIdx.y * gridDim.x + blockIdx.x;
    const int nid = (fid & 7) * 192 + (fid >> 3);
    const int m  = nid >> 4;
    const int l0 = (nid & 15) * 64;

    const int tid = threadIdx.x;
    const int tx = tid & 15, ty = tid >> 4;
    const int tx4 = tx * 4, ty4 = ty * 4;

    // stage Q once
    #pragma unroll
    for (int q = 0; q < 4; ++q) {
        int idx = tid + q * 256;
        int r = idx >> 4, g = idx & 15;
        Qf4[r * 16 + g] = *reinterpret_cast<const float4*>(
            Qt + (((size_t)(m * 64 + r)) << 10) + l0 + g * 4);
    }

    float lpart[4] = {0.f, 0.f, 0.f, 0.f};
    float o[4][4] = {};

    const size_t mbase = (size_t)m * Lq * Lq;

    for (int s0 = 0; s0 < Lq; s0 += 64) {
        __syncthreads();   // prev PV readers done (V, P=Kbuf); orders Q stage iter0
        #pragma unroll
        for (int q = 0; q < 4; ++q) {
            int idx = tid + q * 256;
            int r = idx >> 4, g = idx & 15;
            Kf4[r * 16 + g] = *reinterpret_cast<const float4*>(
                Kt + (((size_t)(m * 64 + r)) << 10) + s0 + g * 4);
        }
        #pragma unroll
        for (int q = 0; q < 2; ++q) {
            int idx = tid + q * 256;
            int r = idx >> 3, gg = idx & 7;
            union { uint4 u4; unsigned short us[8]; } ld;
            ld.u4 = *reinterpret_cast<const uint4*>(
                Vh + ((size_t)m * Lq + s0 + r) * 64 + gg * 8);
            Vf4[r * 16 + gg * 2 + 0] = make_float4(
                bfbits2f(ld.us[0]), bfbits2f(ld.us[1]),
                bfbits2f(ld.us[2]), bfbits2f(ld.us[3]));
            Vf4[r * 16 + gg * 2 + 1] = make_float4(
                bfbits2f(ld.us[4]), bfbits2f(ld.us[5]),
                bfbits2f(ld.us[6]), bfbits2f(ld.us[7]));
        }
        __syncthreads();

        // QK^T
        float acc[4][4] = {};
        #pragma unroll 8
        for (int d = 0; d < 64; ++d) {
            float4 q4 = Qf4[d * 16 + ty];
            float4 k4 = Kf4[d * 16 + tx];
            float a[4] = {q4.x, q4.y, q4.z, q4.w};
            float bb[4] = {k4.x, k4.y, k4.z, k4.w};
            #pragma unroll
            for (int i = 0; i < 4; ++i)
                #pragma unroll
                for (int j = 0; j < 4; ++j)
                    acc[i][j] = fmaf(a[i], bb[j], acc[i][j]);
        }

        // p = exp(s*scale) (safe: |s*scale| <~ 30 << 88), row-sum, store p
        #pragma unroll
        for (int i = 0; i < 4; ++i) {
            acc[i][0] = __expf(acc[i][0] * SCALE);
            acc[i][1] = __expf(acc[i][1] * SCALE);
            acc[i][2] = __expf(acc[i][2] * SCALE);
            acc[i][3] = __expf(acc[i][3] * SCALE);
            lpart[i] += acc[i][0] + acc[i][1] + acc[i][2] + acc[i][3];
            if (usews) {
                union { unsigned short u[4]; uint2 v2; } pk;
                #pragma unroll
                for (int j = 0; j < 4; ++j) pk.u[j] = f2bf(acc[i][j]);
                *reinterpret_cast<uint2*>(
                    pws + ((size_t)m << 20) + ((size_t)(l0 + ty4 + i) << 10)
                        + s0 + tx4) = pk.v2;
            } else {
                *reinterpret_cast<float4*>(
                    attn_out + mbase + (size_t)(l0 + ty4 + i) * Lq + s0 + tx4) =
                    make_float4(acc[i][0], acc[i][1], acc[i][2], acc[i][3]);
            }
        }

        __syncthreads();   // all QK reads of Kbuf done -> safe to overwrite with P~

        // P~ transposed [s][l] into K's buffer, XOR-swizzled
        #pragma unroll
        for (int j = 0; j < 4; ++j) {
            int srow = tx4 + j;
            Pf4[srow * 16 + (ty ^ (srow & 15))] =
                make_float4(acc[0][j], acc[1][j], acc[2][j], acc[3][j]);
        }
        __syncthreads();

        // O += P~ . V
        #pragma unroll 8
        for (int ss = 0; ss < 64; ++ss) {
            float4 p4 = Pf4[ss * 16 + (ty ^ (ss & 15))];
            float4 v4 = Vf4[ss * 16 + tx];
            float a[4] = {p4.x, p4.y, p4.z, p4.w};
            float bb[4] = {v4.x, v4.y, v4.z, v4.w};
            #pragma unroll
            for (int i = 0; i < 4; ++i)
                #pragma unroll
                for (int j = 0; j < 4; ++j)
                    o[i][j] = fmaf(a[i], bb[j], o[i][j]);
        }
    }

    // row-sum reduce -> inverse
    float inv[4];
    #pragma unroll
    for (int i = 0; i < 4; ++i) {
        float ls = lpart[i];
        ls += __shfl_xor(ls, 1);
        ls += __shfl_xor(ls, 2);
        ls += __shfl_xor(ls, 4);
        ls += __shfl_xor(ls, 8);
        inv[i] = 1.0f / ls;
    }

    // O write: bf16 transposed [dd][l]
    #pragma unroll
    for (int j = 0; j < 4; ++j) {
        union { unsigned short u[4]; uint2 v2; } pk;
        #pragma unroll
        for (int i = 0; i < 4; ++i) pk.u[i] = f2bf(o[i][j] * inv[i]);
        *reinterpret_cast<uint2*>(
            Ot + (((size_t)(m * 64 + tx4 + j)) << 10) + l0 + ty4) = pk.v2;
    }

    if (usews) {
        // share inv across block, then fully-coalesced normalize
        if (tx == 0) {
            #pragma unroll
            for (int i = 0; i < 4; ++i) Linv[ty4 + i] = inv[i];
        }
        __syncthreads();
        const unsigned short* pb = pws + ((size_t)m << 20);
        #pragma unroll 4
        for (int k2 = 0; k2 < 32; ++k2) {
            int unit = tid + k2 * 256;       // 8192 units of 8 elems
            int row = unit >> 7, c8 = (unit & 127) * 8;
            union { uint4 u4; unsigned short us[8]; } ld;
            ld.u4 = *reinterpret_cast<const uint4*>(
                pb + ((size_t)(l0 + row) << 10) + c8);
            float iv = Linv[row];
            float4 f0 = make_float4(bfbits2f(ld.us[0]) * iv, bfbits2f(ld.us[1]) * iv,
                                    bfbits2f(ld.us[2]) * iv, bfbits2f(ld.us[3]) * iv);
            float4 f1 = make_float4(bfbits2f(ld.us[4]) * iv, bfbits2f(ld.us[5]) * iv,
                                    bfbits2f(ld.us[6]) * iv, bfbits2f(ld.us[7]) * iv);
            float* dst = attn_out + mbase + ((size_t)(l0 + row) << 10) + c8;
            *reinterpret_cast<float4*>(dst)     = f0;
            *reinterpret_cast<float4*>(dst + 4) = f1;
        }
    } else {
        // in-place normalize: each thread re-reads exactly what it wrote
        #pragma unroll
        for (int i = 0; i < 4; ++i) {
            const float iv = inv[i];
            size_t base = mbase + (size_t)(l0 + ty4 + i) * Lq + tx4;
            #pragma unroll 4
            for (int s0 = 0; s0 < Lq; s0 += 64) {
                float4 xv = *reinterpret_cast<float4*>(attn_out + base + s0);
                xv.x *= iv; xv.y *= iv; xv.z *= iv; xv.w *= iv;
                *reinterpret_cast<float4*>(attn_out + base + s0) = xv;
            }
        }
    }
}

// ---------------------------------------------------------------------------
// Kernel 3: out[b,e,v,l] = sum_{h,dd} Wo[e][h*64+dd] * O[m][dd][l].
// Tile: 256 l x 64 e, K-step 32. grid: 384 blocks (4,8,12), chunk-swizzled.
// ---------------------------------------------------------------------------
__global__ __launch_bounds__(256, 4) void oproj_kernel(
    const float* __restrict__ Wo, const bf16* __restrict__ Ot,
    float* __restrict__ out)
{
    __shared__ float4 Of4[32 * 64];   // [dd][l] natural, 32 KiB
    __shared__ float4 Wf4[32 * 16];   // [d][e] transposed swizzled, 8 KiB
    float* Ws = reinterpret_cast<float*>(Wf4);

    const int fid = (blockIdx.z * gridDim.y + blockIdx.y) * gridDim.x + blockIdx.x;
    const int nid = (fid & 7) * 48 + (fid >> 3);
    const int x_  = nid & 3;
    const int y_  = (nid >> 2) & 7;
    const int pl  = nid >> 5;
    const int b   = pl / V3;
    const int v   = pl % V3;

    const int l0 = x_ * 256;
    const int e0 = y_ * 64;

    const int tid = threadIdx.x;
    const int txl = tid & 15;
    const int tye = tid >> 4;

    float acc[16][4] = {};

    for (int ph = 0; ph < 16; ++ph) {
        const int h = ph >> 1;
        const int dd0 = (ph & 1) * 32;
        const int m = (b * Hh + h) * V3 + v;
        __syncthreads();
        // stage O [dd][l] bf16->f32: 1024 uint4 loads, 2 f4 LDS writes each
        #pragma unroll
        for (int q2 = 0; q2 < 4; ++q2) {
            int idx = tid + q2 * 256;
            int r = idx >> 5, g = idx & 31;
            union { uint4 u4; unsigned short us[8]; } ld;
            ld.u4 = *reinterpret_cast<const uint4*>(
                Ot + (((size_t)(m * 64 + dd0 + r)) << 10) + l0 + g * 8);
            Of4[r * 64 + g * 2 + 0] = make_float4(
                bfbits2f(ld.us[0]), bfbits2f(ld.us[1]),
                bfbits2f(ld.us[2]), bfbits2f(ld.us[3]));
            Of4[r * 64 + g * 2 + 1] = make_float4(
                bfbits2f(ld.us[4]), bfbits2f(ld.us[5]),
                bfbits2f(ld.us[6]), bfbits2f(ld.us[7]));
        }
        // stage Wo transposed [d][e], swizzled
        #pragma unroll
        for (int q2 = 0; q2 < 2; ++q2) {
            int idx = tid + q2 * 256;
            int erow = idx >> 3, g = idx & 7;
            float4 wv4 = *reinterpret_cast<const float4*>(
                Wo + (size_t)(e0 + erow) * Dm + h * 64 + dd0 + g * 4);
            float wz[4] = {wv4.x, wv4.y, wv4.z, wv4.w};
            #pragma unroll
            for (int di = 0; di < 4; ++di) {
                int d = g * 4 + di;
                Ws[d * 64 + (((erow >> 2) ^ (d & 15)) << 2) + (erow & 3)] = wz[di];
            }
        }
        __syncthreads();

        #pragma unroll 4
        for (int kk = 0; kk < 32; ++kk) {
            float4 b4 = Wf4[kk * 16 + (tye ^ (kk & 15))];
            float bb[4] = {b4.x, b4.y, b4.z, b4.w};
            float a[16];
            #pragma unroll
            for (int u = 0; u < 4; ++u) {
                float4 a4 = Of4[kk * 64 + u * 16 + txl];
                a[u*4+0] = a4.x; a[u*4+1] = a4.y; a[u*4+2] = a4.z; a[u*4+3] = a4.w;
            }
            #pragma unroll
            for (int i = 0; i < 16; ++i)
                #pragma unroll
                for (int j = 0; j < 4; ++j)
                    acc[i][j] = fmaf(a[i], bb[j], acc[i][j]);
        }
    }

    #pragma unroll
    for (int j = 0; j < 4; ++j) {
        #pragma unroll
        for (int u = 0; u < 4; ++u) {
            float4 f4 = make_float4(acc[u*4+0][j], acc[u*4+1][j],
                                    acc[u*4+2][j], acc[u*4+3][j]);
            size_t off = ((size_t)(b * Dm + e0 + tye * 4 + j) * V3 + v) * Lq
                       + l0 + u * 64 + txl * 4;
            *reinterpret_cast<float4*>(out + off) = f4;
        }
    }
}

// ---------------------------------------------------------------------------
extern "C" void kernel_launch(void* const* d_in, const int* in_sizes, int n_in,
                              void* d_out, int out_size, void* d_ws, size_t ws_size,
                              hipStream_t stream)
{
    const float* q  = (const float*)d_in[0];
    const float* k  = (const float*)d_in[1];
    const float* vv = (const float*)d_in[2];
    const float* Wq = (const float*)d_in[3];
    const float* Wk = (const float*)d_in[4];
    const float* Wv = (const float*)d_in[5];
    const float* Wo = (const float*)d_in[6];

    float* out      = (float*)d_out;
    float* attn_out = out + (size_t)Bn * Dm * V3 * Lq;   // 6,291,456 elems in

    // workspace layout (bytes):
    //   Qt fp32 transposed [m][dd][l] : [0,        25165824)
    //   Kt fp32 transposed [m][dd][l] : [25165824, 50331648)
    //   Vh bf16 natural    [m][l][dd] : [50331648, 62914560)
    //   Ot bf16 transposed [m][dd][l] : [62914560, 75497472)
    //   Pw bf16 raw-p      [m][l][s]  : [75497472, 276824064)  (optional)
    char* w = (char*)d_ws;
    float* Qt = (float*)(w);
    float* Kt = (float*)(w + 25165824);
    bf16*  Vh = (bf16*) (w + 50331648);
    bf16*  Ot = (bf16*) (w + 62914560);
    unsigned short* Pw = (unsigned short*)(w + 75497472);
    const int usews = (ws_size >= (size_t)75497472 + (size_t)NM * Lq * Lq * 2) ? 1 : 0;

    dim3 b256(256);

    proj_all_kernel<<<dim3(4, 8, 36), b256, 0, stream>>>(
        q, k, vv, Wq, Wk, Wv, Qt, Kt, Vh);

    fused_attn_kernel<<<dim3(Lq / 64, NM), b256, 0, stream>>>(
        Qt, Kt, Vh, attn_out, Ot, Pw, usews);

    oproj_kernel<<<dim3(4, 8, 12), b256, 0, stream>>>(Wo, Ot, out);
}

// Round 5
// 913.559 us; speedup vs baseline: 1.4734x; 1.4734x over previous
//
#include <hip/hip_runtime.h>
#include <hip/hip_bf16.h>

typedef __hip_bfloat16 bf16;
using bf16x8 = __attribute__((ext_vector_type(8))) short;   // MFMA A/B frag (4 VGPR)
using f32x4  = __attribute__((ext_vector_type(4))) float;   // MFMA C/D frag

#define Bn 4
#define Dm 512
#define Hh 8
#define V3 3
#define Lq 1024
#define NM (Bn*Hh*V3)   // 96 attention maps

__device__ __forceinline__ unsigned short f2bf(float x) {
    bf16 h = __float2bfloat16(x);
    return *reinterpret_cast<unsigned short*>(&h);
}
__device__ __forceinline__ float bfbits2f(unsigned short u) {
    return __uint_as_float((unsigned)u << 16);
}

constexpr float SCALE = 0.57735026919f; // 1/sqrt(3)

// ---------------------------------------------------------------------------
// Kernel 1: ALL THREE projections (R3 geometry: 128l x 64e, K-step 32).
// Q,K: split bf16 hi/lo, natural [m][l][dd] (via LDS bounce, coalesced).
// V:   bf16 transposed [m][dd][l].
// grid: (8,8,36) = 2304 blocks, chunk-swizzled over XCDs (2304 = 8*288).
// ---------------------------------------------------------------------------
__global__ __launch_bounds__(256, 4) void proj_all_kernel(
    const float* __restrict__ xq, const float* __restrict__ xk,
    const float* __restrict__ xv,
    const float* __restrict__ Wq, const float* __restrict__ Wk,
    const float* __restrict__ Wv,
    unsigned short* __restrict__ Qh, unsigned short* __restrict__ Ql,
    unsigned short* __restrict__ Kh, unsigned short* __restrict__ Kl,
    unsigned short* __restrict__ Vt)
{
    __shared__ float4 ldsblk[2048];             // 32 KiB
    float4* Xf4 = ldsblk;                       // [32][128] floats (16 KiB)
    float*  Ws  = (float*)(ldsblk + 1024);      // [32][64] transposed swizzled (8 KiB)
    float4* Wf4 = ldsblk + 1024;

    const int fid = (blockIdx.z * gridDim.y + blockIdx.y) * gridDim.x + blockIdx.x;
    const int nid = (fid & 7) * 288 + (fid >> 3);
    const int x_  = nid & 7;          // l-block (8)
    const int y_  = (nid >> 3) & 7;   // e-block (8)
    const int zz  = nid >> 6;         // 0..35
    const int pid = zz / 12;          // 0=Q 1=K 2=V
    const int pl  = zz % 12;
    const int b   = pl / V3;
    const int v   = pl % V3;

    const float* xsrc = (pid == 0) ? xq : (pid == 1) ? xk : xv;
    const float* W    = (pid == 0) ? Wq : (pid == 1) ? Wk : Wv;

    const int l0 = x_ * 128;
    const int e0 = y_ * 64;
    const int h  = y_;
    const int m  = (b * Hh + h) * V3 + v;

    const int tid = threadIdx.x;
    const int txl = tid & 15;
    const int tye = tid >> 4;

    float acc[8][4] = {};

    for (int ph = 0; ph < 16; ++ph) {
        const int d0 = ph * 32;
        __syncthreads();
        #pragma unroll
        for (int q2 = 0; q2 < 4; ++q2) {
            int idx = tid + q2 * 256;
            int r = idx >> 5, g = idx & 31;
            Xf4[r * 32 + g] = *reinterpret_cast<const float4*>(
                xsrc + ((size_t)(b * Dm + d0 + r) * V3 + v) * Lq + l0 + g * 4);
        }
        #pragma unroll
        for (int q2 = 0; q2 < 2; ++q2) {
            int idx = tid + q2 * 256;
            int erow = idx >> 3, g = idx & 7;
            float4 wv4 = *reinterpret_cast<const float4*>(
                W + (size_t)(e0 + erow) * Dm + d0 + g * 4);
            float wz[4] = {wv4.x, wv4.y, wv4.z, wv4.w};
            #pragma unroll
            for (int di = 0; di < 4; ++di) {
                int d = g * 4 + di;
                Ws[d * 64 + (((erow >> 2) ^ (d & 15)) << 2) + (erow & 3)] = wz[di];
            }
        }
        __syncthreads();

        #pragma unroll 8
        for (int kk = 0; kk < 32; ++kk) {
            float4 alo = Xf4[kk * 32 + txl];
            float4 ahi = Xf4[kk * 32 + 16 + txl];
            float4 b4  = Wf4[kk * 16 + (tye ^ (kk & 15))];
            float a[8] = {alo.x, alo.y, alo.z, alo.w, ahi.x, ahi.y, ahi.z, ahi.w};
            float bb[4] = {b4.x, b4.y, b4.z, b4.w};
            #pragma unroll
            for (int i = 0; i < 8; ++i)
                #pragma unroll
                for (int j = 0; j < 4; ++j)
                    acc[i][j] = fmaf(a[i], bb[j], acc[i][j]);
        }
    }

    __syncthreads();   // done reading Xf4/Ws; LDS reusable

    if (pid < 2) {
        // bounce acc -> LDS [128 l][16 f4-slot] with slot XOR, then split-write
        float4* Ys4 = ldsblk;   // 32 KiB: [128][16] f4
        #pragma unroll
        for (int i = 0; i < 8; ++i) {
            int u = i >> 2, ii = i & 3;
            int lloc = u * 64 + txl * 4 + ii;
            int slot = tye ^ (txl & 3);    // == tye ^ ((lloc>>2)&3)
            Ys4[lloc * 16 + slot] =
                make_float4(acc[i][0], acc[i][1], acc[i][2], acc[i][3]);
        }
        __syncthreads();
        unsigned short* Oh_ = (pid == 0) ? Qh : Kh;
        unsigned short* Ol_ = (pid == 0) ? Ql : Kl;
        const int r = tid >> 1, half = tid & 1;
        unsigned hw[16], lw[16];
        #pragma unroll
        for (int c4 = 0; c4 < 8; ++c4) {
            int lc4 = half * 8 + c4;
            float4 t = Ys4[r * 16 + (lc4 ^ ((r >> 2) & 3))];
            float e4[4] = {t.x, t.y, t.z, t.w};
            unsigned short hs[4], ls[4];
            #pragma unroll
            for (int e = 0; e < 4; ++e) {
                hs[e] = f2bf(e4[e]);
                ls[e] = f2bf(e4[e] - bfbits2f(hs[e]));
            }
            hw[c4*2+0] = (unsigned)hs[0] | ((unsigned)hs[1] << 16);
            hw[c4*2+1] = (unsigned)hs[2] | ((unsigned)hs[3] << 16);
            lw[c4*2+0] = (unsigned)ls[0] | ((unsigned)ls[1] << 16);
            lw[c4*2+1] = (unsigned)ls[2] | ((unsigned)ls[3] << 16);
        }
        size_t gb = ((size_t)m * Lq + l0 + r) * 64 + half * 32;
        #pragma unroll
        for (int k2 = 0; k2 < 4; ++k2) {
            *reinterpret_cast<uint4*>(Oh_ + gb + k2 * 8) =
                make_uint4(hw[k2*4], hw[k2*4+1], hw[k2*4+2], hw[k2*4+3]);
            *reinterpret_cast<uint4*>(Ol_ + gb + k2 * 8) =
                make_uint4(lw[k2*4], lw[k2*4+1], lw[k2*4+2], lw[k2*4+3]);
        }
    } else {
        // V: bf16 transposed [m][dd][l]
        #pragma unroll
        for (int j = 0; j < 4; ++j) {
            int dd = tye * 4 + j;
            #pragma unroll
            for (int u = 0; u < 2; ++u) {
                union { unsigned short s[4]; uint2 v2; } pk;
                #pragma unroll
                for (int ii = 0; ii < 4; ++ii) pk.s[ii] = f2bf(acc[u*4+ii][j]);
                *reinterpret_cast<uint2*>(
                    Vt + (((size_t)(m * 64 + dd)) << 10) + l0 + u * 64 + txl * 4)
                    = pk.v2;
            }
        }
    }
}

// ---------------------------------------------------------------------------
// Kernel 2: MFMA fused attention, two-pass, no-max softmax.
// Per block: 64 q-rows of one map. Pass1: QK^T (split-bf16, 3-term) -> row
// sums. Pass2: recompute, write normalized attn fp32 once, P(bf16) -> LDS,
// O += P.V via MFMA. 4 waves; wave w owns s-cols w*16.. (QK) / l-rows w*16..
// (PV). All LDS tiles XOR-swizzled byte^=((row&7)<<4).
// grid: dim3(16, 96) = 1536 blocks, XCD-chunk swizzled. LDS ~33 KiB.
// ---------------------------------------------------------------------------
__device__ __forceinline__ void stage_tile64(
    unsigned char* dst, const unsigned short* __restrict__ src,
    size_t row_stride, int tid)
{
    #pragma unroll
    for (int q = 0; q < 2; ++q) {
        int u = tid + q * 256;              // 512 units of 16B
        int row = u >> 3, off = u & 7;
        uint4 d = *reinterpret_cast<const uint4*>(src + (size_t)row * row_stride + off * 8);
        *reinterpret_cast<uint4*>(dst + ((row * 128 + off * 16) ^ ((row & 7) << 4))) = d;
    }
}

__global__ __launch_bounds__(256) void fused_attn_kernel(
    const unsigned short* __restrict__ Qh, const unsigned short* __restrict__ Ql,
    const unsigned short* __restrict__ Kh, const unsigned short* __restrict__ Kl,
    const unsigned short* __restrict__ Vt, float* __restrict__ attn_out,
    unsigned short* __restrict__ Ot)
{
    __shared__ float4 ldsf4[2128];   // 34048 B
    unsigned char* L   = (unsigned char*)ldsf4;
    unsigned char* Lkh = L;            // 8 KiB  K-hi [s][dd]
    unsigned char* Lkl = L + 8192;     // 8 KiB  K-lo
    unsigned char* Lvt = L + 16384;    // 8 KiB  V^T [dd][s]
    unsigned char* Lp  = L + 24576;    // 8 KiB  P bf16 [l][s]
    float* rowsumW = (float*)(L + 32768);   // [4][64]
    float* invrow  = (float*)(L + 33792);   // [64]

    const int fid = blockIdx.y * gridDim.x + blockIdx.x;
    const int nid = (fid & 7) * 192 + (fid >> 3);
    const int m  = nid >> 4;
    const int l0 = (nid & 15) * 64;

    const int tid = threadIdx.x;
    const int w    = tid >> 6;
    const int ln   = tid & 63;
    const int ln15 = ln & 15;
    const int lq   = ln >> 4;
    const int sc   = w * 16;          // this wave's s-columns (QK)

    // ---- preload Q fragments (hi+lo) into registers via LDS bounce ----
    stage_tile64(Lkh, Qh + ((size_t)m * Lq + l0) * 64, 64, tid);
    stage_tile64(Lkl, Ql + ((size_t)m * Lq + l0) * 64, 64, tid);
    __syncthreads();
    bf16x8 qfh[4][2], qfl[4][2];
    #pragma unroll
    for (int lt = 0; lt < 4; ++lt) {
        int row = lt * 16 + ln15;
        #pragma unroll
        for (int kq = 0; kq < 2; ++kq) {
            int byte = (row * 128 + kq * 64 + lq * 16) ^ ((row & 7) << 4);
            qfh[lt][kq] = *reinterpret_cast<const bf16x8*>(Lkh + byte);
            qfl[lt][kq] = *reinterpret_cast<const bf16x8*>(Lkl + byte);
        }
    }
    __syncthreads();

    const size_t mbase = (size_t)m * Lq * Lq;
    const unsigned short* Khm = Kh + (size_t)m * Lq * 64;
    const unsigned short* Klm = Kl + (size_t)m * Lq * 64;
    const unsigned short* Vtm = Vt + (((size_t)m * 64) << 10);

    // ================= pass 1: row sums =================
    float lsum[4][4] = {};
    for (int s0 = 0; s0 < Lq; s0 += 64) {
        stage_tile64(Lkh, Khm + (size_t)s0 * 64, 64, tid);
        stage_tile64(Lkl, Klm + (size_t)s0 * 64, 64, tid);
        __syncthreads();
        bf16x8 bh[2], bl[2];
        #pragma unroll
        for (int kq = 0; kq < 2; ++kq) {
            int row = sc + ln15;
            int byte = (row * 128 + kq * 64 + lq * 16) ^ ((row & 7) << 4);
            bh[kq] = *reinterpret_cast<const bf16x8*>(Lkh + byte);
            bl[kq] = *reinterpret_cast<const bf16x8*>(Lkl + byte);
        }
        #pragma unroll
        for (int lt = 0; lt < 4; ++lt) {
            f32x4 c = (f32x4)0.f;
            #pragma unroll
            for (int kq = 0; kq < 2; ++kq) {
                c = __builtin_amdgcn_mfma_f32_16x16x32_bf16(qfh[lt][kq], bh[kq], c, 0, 0, 0);
                c = __builtin_amdgcn_mfma_f32_16x16x32_bf16(qfl[lt][kq], bh[kq], c, 0, 0, 0);
                c = __builtin_amdgcn_mfma_f32_16x16x32_bf16(qfh[lt][kq], bl[kq], c, 0, 0, 0);
            }
            #pragma unroll
            for (int r = 0; r < 4; ++r)
                lsum[lt][r] += __expf(c[r] * SCALE);
        }
        __syncthreads();
    }
    // reduce row sums across the 16 lanes of each row group, then across waves
    #pragma unroll
    for (int lt = 0; lt < 4; ++lt)
        #pragma unroll
        for (int r = 0; r < 4; ++r) {
            float vv = lsum[lt][r];
            vv += __shfl_xor(vv, 1);
            vv += __shfl_xor(vv, 2);
            vv += __shfl_xor(vv, 4);
            vv += __shfl_xor(vv, 8);
            if (ln15 == 0) rowsumW[w * 64 + lt * 16 + lq * 4 + r] = vv;
        }
    __syncthreads();
    if (tid < 64)
        invrow[tid] = 1.0f / (rowsumW[tid] + rowsumW[64 + tid] +
                              rowsumW[128 + tid] + rowsumW[192 + tid]);
    __syncthreads();

    // ================= pass 2: attn write + PV =================
    f32x4 o[4];
    o[0] = (f32x4)0.f; o[1] = (f32x4)0.f; o[2] = (f32x4)0.f; o[3] = (f32x4)0.f;

    for (int s0 = 0; s0 < Lq; s0 += 64) {
        stage_tile64(Lkh, Khm + (size_t)s0 * 64, 64, tid);
        stage_tile64(Lkl, Klm + (size_t)s0 * 64, 64, tid);
        stage_tile64(Lvt, Vtm + s0, 1024, tid);
        __syncthreads();
        bf16x8 bh[2], bl[2];
        #pragma unroll
        for (int kq = 0; kq < 2; ++kq) {
            int row = sc + ln15;
            int byte = (row * 128 + kq * 64 + lq * 16) ^ ((row & 7) << 4);
            bh[kq] = *reinterpret_cast<const bf16x8*>(Lkh + byte);
            bl[kq] = *reinterpret_cast<const bf16x8*>(Lkl + byte);
        }
        #pragma unroll
        for (int lt = 0; lt < 4; ++lt) {
            f32x4 c = (f32x4)0.f;
            #pragma unroll
            for (int kq = 0; kq < 2; ++kq) {
                c = __builtin_amdgcn_mfma_f32_16x16x32_bf16(qfh[lt][kq], bh[kq], c, 0, 0, 0);
                c = __builtin_amdgcn_mfma_f32_16x16x32_bf16(qfl[lt][kq], bh[kq], c, 0, 0, 0);
                c = __builtin_amdgcn_mfma_f32_16x16x32_bf16(qfh[lt][kq], bl[kq], c, 0, 0, 0);
            }
            #pragma unroll
            for (int r = 0; r < 4; ++r) {
                int l = lt * 16 + lq * 4 + r;
                float p = __expf(c[r] * SCALE) * invrow[l];
                attn_out[mbase + (size_t)(l0 + l) * Lq + s0 + sc + ln15] = p;
                int byte = (l * 128 + (sc + ln15) * 2) ^ ((l & 7) << 4);
                *reinterpret_cast<unsigned short*>(Lp + byte) = f2bf(p);
            }
        }
        __syncthreads();   // P visible to all waves
        {
            int prow = w * 16 + ln15;   // PV A rows: this wave's l-strip
            #pragma unroll
            for (int kq = 0; kq < 2; ++kq) {
                bf16x8 pa = *reinterpret_cast<const bf16x8*>(
                    Lp + ((prow * 128 + kq * 64 + lq * 16) ^ ((prow & 7) << 4)));
                #pragma unroll
                for (int nt = 0; nt < 4; ++nt) {
                    int vrow = nt * 16 + ln15;
                    bf16x8 vb = *reinterpret_cast<const bf16x8*>(
                        Lvt + ((vrow * 128 + kq * 64 + lq * 16) ^ ((vrow & 7) << 4)));
                    o[nt] = __builtin_amdgcn_mfma_f32_16x16x32_bf16(pa, vb, o[nt], 0, 0, 0);
                }
            }
        }
        __syncthreads();   // PV reads done; safe to restage
    }

    // ---- O epilogue: frags -> LDS [dd][l] fp32 (swizzled) -> coalesced bf16 ----
    float* Olds = (float*)L;   // 16 KiB over Lkh+Lkl
    #pragma unroll
    for (int nt = 0; nt < 4; ++nt) {
        int dd = nt * 16 + ln15;
        int byte = (dd * 256 + (w * 16 + lq * 4) * 4) ^ ((dd & 7) << 4);
        *reinterpret_cast<f32x4*>((unsigned char*)Olds + byte) = o[nt];
    }
    __syncthreads();
    {
        int dd = tid >> 2, c = tid & 3;
        unsigned ow[8];
        #pragma unroll
        for (int k2 = 0; k2 < 4; ++k2) {
            int byte = (dd * 256 + c * 64 + k2 * 16) ^ ((dd & 7) << 4);
            f32x4 t = *reinterpret_cast<const f32x4*>((unsigned char*)Olds + byte);
            ow[k2*2+0] = (unsigned)f2bf(t[0]) | ((unsigned)f2bf(t[1]) << 16);
            ow[k2*2+1] = (unsigned)f2bf(t[2]) | ((unsigned)f2bf(t[3]) << 16);
        }
        size_t base = (((size_t)(m * 64 + dd)) << 10) + l0 + c * 16;
        *reinterpret_cast<uint4*>(Ot + base)     = make_uint4(ow[0], ow[1], ow[2], ow[3]);
        *reinterpret_cast<uint4*>(Ot + base + 8) = make_uint4(ow[4], ow[5], ow[6], ow[7]);
    }
}

// ---------------------------------------------------------------------------
// Kernel 3: out[b,e,v,l] = sum_{h,dd} Wo[e][h*64+dd] * O[m][dd][l]  (R3 ver).
// grid: (8,8,12) = 768 blocks, chunk-swizzled (768 = 8*96).
// ---------------------------------------------------------------------------
__global__ __launch_bounds__(256, 4) void oproj_kernel(
    const float* __restrict__ Wo, const unsigned short* __restrict__ Ot,
    float* __restrict__ out)
{
    __shared__ float Os[32 * 128];  // [dd][l], f4-XOR-swizzled by row
    __shared__ float Ws[32 * 64];   // [d][e] transposed, swizzled
    float4* Of4 = reinterpret_cast<float4*>(Os);
    float4* Wf4 = reinterpret_cast<float4*>(Ws);

    const int fid = (blockIdx.z * gridDim.y + blockIdx.y) * gridDim.x + blockIdx.x;
    const int nid = (fid & 7) * 96 + (fid >> 3);
    const int x_  = nid & 7;
    const int y_  = (nid >> 3) & 7;
    const int pl  = nid >> 6;
    const int b   = pl / V3;
    const int v   = pl % V3;

    const int l0 = x_ * 128;
    const int e0 = y_ * 64;

    const int tid = threadIdx.x;
    const int txl = tid & 15;
    const int tye = tid >> 4;

    float acc[8][4] = {};

    for (int ph = 0; ph < 16; ++ph) {
        const int h = ph >> 1;
        const int dd0 = (ph & 1) * 32;
        const int m = (b * Hh + h) * V3 + v;
        __syncthreads();
        #pragma unroll
        for (int q2 = 0; q2 < 2; ++q2) {
            int idx = tid + q2 * 256;
            int r = idx >> 4, g = idx & 15;
            union { uint4 u4; unsigned short us[8]; } ld;
            ld.u4 = *reinterpret_cast<const uint4*>(
                Ot + (((size_t)(m * 64 + dd0 + r)) << 10) + l0 + g * 8);
            Of4[r * 32 + ((g * 2 + 0) ^ (r & 31))] = make_float4(
                bfbits2f(ld.us[0]), bfbits2f(ld.us[1]),
                bfbits2f(ld.us[2]), bfbits2f(ld.us[3]));
            Of4[r * 32 + ((g * 2 + 1) ^ (r & 31))] = make_float4(
                bfbits2f(ld.us[4]), bfbits2f(ld.us[5]),
                bfbits2f(ld.us[6]), bfbits2f(ld.us[7]));
        }
        #pragma unroll
        for (int q2 = 0; q2 < 2; ++q2) {
            int idx = tid + q2 * 256;
            int erow = idx >> 3, g = idx & 7;
            float4 wv4 = *reinterpret_cast<const float4*>(
                Wo + (size_t)(e0 + erow) * Dm + h * 64 + dd0 + g * 4);
            float wz[4] = {wv4.x, wv4.y, wv4.z, wv4.w};
            #pragma unroll
            for (int di = 0; di < 4; ++di) {
                int d = g * 4 + di;
                Ws[d * 64 + (((erow >> 2) ^ (d & 15)) << 2) + (erow & 3)] = wz[di];
            }
        }
        __syncthreads();

        #pragma unroll 8
        for (int kk = 0; kk < 32; ++kk) {
            float4 alo = Of4[kk * 32 + (txl ^ (kk & 31))];
            float4 ahi = Of4[kk * 32 + ((16 + txl) ^ (kk & 31))];
            float4 b4  = Wf4[kk * 16 + (tye ^ (kk & 15))];
            float a[8] = {alo.x, alo.y, alo.z, alo.w, ahi.x, ahi.y, ahi.z, ahi.w};
            float bb[4] = {b4.x, b4.y, b4.z, b4.w};
            #pragma unroll
            for (int i = 0; i < 8; ++i)
                #pragma unroll
                for (int j = 0; j < 4; ++j)
                    acc[i][j] = fmaf(a[i], bb[j], acc[i][j]);
        }
    }

    #pragma unroll
    for (int i = 0; i < 8; ++i) {
        int e = e0 + tye * 4;
        (void)e;
    }
    #pragma unroll
    for (int j = 0; j < 4; ++j) {
        #pragma unroll
        for (int u = 0; u < 2; ++u) {
            float4 f4 = make_float4(acc[u*4+0][j], acc[u*4+1][j],
                                    acc[u*4+2][j], acc[u*4+3][j]);
            size_t off = ((size_t)(b * Dm + e0 + tye * 4 + j) * V3 + v) * Lq
                       + l0 + u * 64 + txl * 4;
            *reinterpret_cast<float4*>(out + off) = f4;
        }
    }
}

// ---------------------------------------------------------------------------
extern "C" void kernel_launch(void* const* d_in, const int* in_sizes, int n_in,
                              void* d_out, int out_size, void* d_ws, size_t ws_size,
                              hipStream_t stream)
{
    const float* q  = (const float*)d_in[0];
    const float* k  = (const float*)d_in[1];
    const float* vv = (const float*)d_in[2];
    const float* Wq = (const float*)d_in[3];
    const float* Wk = (const float*)d_in[4];
    const float* Wv = (const float*)d_in[5];
    const float* Wo = (const float*)d_in[6];

    float* out      = (float*)d_out;
    float* attn_out = out + (size_t)Bn * Dm * V3 * Lq;   // 6,291,456 elems in

    // workspace layout (bytes), each buffer 12,582,912 B (bf16 [96][1024][64]):
    //   Qh 0 | Ql 12582912 | Kh 25165824 | Kl 37748736 | Vt 50331648 | Ot 62914560
    char* w = (char*)d_ws;
    unsigned short* Qh = (unsigned short*)(w);
    unsigned short* Ql = (unsigned short*)(w + 12582912);
    unsigned short* Kh = (unsigned short*)(w + 25165824);
    unsigned short* Kl = (unsigned short*)(w + 37748736);
    unsigned short* Vt = (unsigned short*)(w + 50331648);
    unsigned short* Ot = (unsigned short*)(w + 62914560);

    dim3 b256(256);

    proj_all_kernel<<<dim3(8, 8, 36), b256, 0, stream>>>(
        q, k, vv, Wq, Wk, Wv, Qh, Ql, Kh, Kl, Vt);

    fused_attn_kernel<<<dim3(16, NM), b256, 0, stream>>>(
        Qh, Ql, Kh, Kl, Vt, attn_out, Ot);

    oproj_kernel<<<dim3(8, 8, 12), b256, 0, stream>>>(Wo, Ot, out);
}

// Round 6
// 696.252 us; speedup vs baseline: 1.9332x; 1.3121x over previous
//
#include <hip/hip_runtime.h>
#include <hip/hip_bf16.h>

typedef __hip_bfloat16 bf16;
using bf16x8 = __attribute__((ext_vector_type(8))) short;   // MFMA A/B frag (4 VGPR)
using f32x4  = __attribute__((ext_vector_type(4))) float;   // MFMA C/D frag

#define Bn 4
#define Dm 512
#define Hh 8
#define V3 3
#define Lq 1024
#define NM (Bn*Hh*V3)   // 96 attention maps

#define WPITCH 144      // bf16 LDS row pitch in BYTES: 16B-aligned, bank-skewed

__device__ __forceinline__ unsigned short f2bf(float x) {
    bf16 h = __float2bfloat16(x);
    return *reinterpret_cast<unsigned short*>(&h);
}
__device__ __forceinline__ float bfbits2f(unsigned short u) {
    return __uint_as_float((unsigned)u << 16);
}

constexpr float SCALE = 0.57735026919f; // 1/sqrt(3)

// ---------------------------------------------------------------------------
// Kernel 1: ALL THREE projections via MFMA (split-bf16 3-term compensation).
// Y[l,e] = sum_d W[e,d] * x[b,d,v,l] per (b,v).
// A = W rows e (LDS hi/lo, 144B pitch); B = X rows l (global-direct dwords).
// C: row = e (lt*16+lq*4+r), col = l (wave strip w*16 + ln15).
// pid 0 (Q), 1 (K): split bf16 hi/lo natural [m][l][dd].
// pid 2 (V):        bf16 transposed [m][dd][l].
// block 256 (4 waves = 4 l-strips of 16 -> 64 l), tile 64e x 64l, K-tile 64.
// grid (16,8,36) = 4608 blocks, chunk-swizzled (4608 = 8*576).
// ---------------------------------------------------------------------------
__global__ __launch_bounds__(256, 4) void proj_all_kernel(
    const float* __restrict__ xq, const float* __restrict__ xk,
    const float* __restrict__ xv,
    const float* __restrict__ Wq, const float* __restrict__ Wk,
    const float* __restrict__ Wv,
    unsigned short* __restrict__ Qh, unsigned short* __restrict__ Ql,
    unsigned short* __restrict__ Kh, unsigned short* __restrict__ Kl,
    unsigned short* __restrict__ Vt)
{
    __shared__ unsigned char Wlds[2 * 64 * WPITCH];   // Wh | Wl, 18432 B
    unsigned char* LWh = Wlds;
    unsigned char* LWl = Wlds + 64 * WPITCH;

    const int fid = (blockIdx.z * gridDim.y + blockIdx.y) * gridDim.x + blockIdx.x;
    const int nid = (fid & 7) * 576 + (fid >> 3);
    const int x_  = nid & 15;          // l-block (16)
    const int y_  = (nid >> 4) & 7;    // e-block (8) == head
    const int zz  = nid >> 7;          // 0..35
    const int pid = zz / 12;           // 0=Q 1=K 2=V
    const int pl  = zz % 12;
    const int b   = pl / V3;
    const int v   = pl % V3;

    const float* xsrc = (pid == 0) ? xq : (pid == 1) ? xk : xv;
    const float* W    = (pid == 0) ? Wq : (pid == 1) ? Wk : Wv;

    const int l0 = x_ * 64;
    const int e0 = y_ * 64;
    const int m  = (b * Hh + y_) * V3 + v;

    const int tid  = threadIdx.x;
    const int w    = tid >> 6;
    const int ln   = tid & 63;
    const int ln15 = ln & 15;
    const int lq   = ln >> 4;
    const int wl   = w * 16 + ln15;    // this lane's block-local l

    // per-lane X base: x[b, d, v, l0+wl], stride over d = V3*Lq
    const float* xbase = xsrc + (size_t)b * Dm * V3 * Lq + (size_t)v * Lq + l0 + wl;

    f32x4 acc[4];
    #pragma unroll
    for (int i = 0; i < 4; ++i) acc[i] = (f32x4)0.f;

    for (int ph = 0; ph < 8; ++ph) {
        const int d0 = ph * 64;

        // issue X loads early (no LDS dependence): 16 dwords, coalesced over ln15
        float xraw[16];
        #pragma unroll
        for (int kq = 0; kq < 2; ++kq)
            #pragma unroll
            for (int j = 0; j < 8; ++j)
                xraw[kq * 8 + j] =
                    xbase[(size_t)(d0 + kq * 32 + lq * 8 + j) * (V3 * Lq)];

        __syncthreads();   // prior tile's A-frag reads done
        // stage W tile [64e][64d] -> hi/lo bf16 LDS (coalesced f4 reads)
        #pragma unroll
        for (int q2 = 0; q2 < 4; ++q2) {
            int idx  = tid + q2 * 256;
            int row  = idx >> 4;           // e row 0..63
            int dloc = (idx & 15) * 4;     // d chunk
            float4 wv4 = *reinterpret_cast<const float4*>(
                W + (size_t)(e0 + row) * Dm + d0 + dloc);
            float wz[4] = {wv4.x, wv4.y, wv4.z, wv4.w};
            union { unsigned short u[4]; uint2 v2; } hp, lp;
            #pragma unroll
            for (int e = 0; e < 4; ++e) {
                hp.u[e] = f2bf(wz[e]);
                lp.u[e] = f2bf(wz[e] - bfbits2f(hp.u[e]));
            }
            *reinterpret_cast<uint2*>(LWh + row * WPITCH + dloc * 2) = hp.v2;
            *reinterpret_cast<uint2*>(LWl + row * WPITCH + dloc * 2) = lp.v2;
        }
        __syncthreads();

        // build X hi/lo frags from the raw fp32
        bf16x8 xh[2], xl[2];
        #pragma unroll
        for (int kq = 0; kq < 2; ++kq)
            #pragma unroll
            for (int j = 0; j < 8; ++j) {
                float xv_ = xraw[kq * 8 + j];
                unsigned short hs = f2bf(xv_);
                unsigned short ls = f2bf(xv_ - bfbits2f(hs));
                xh[kq][j] = (short)hs;
                xl[kq][j] = (short)ls;
            }

        // MFMA: 3-term split product
        #pragma unroll
        for (int lt = 0; lt < 4; ++lt) {
            int erow = lt * 16 + ln15;
            #pragma unroll
            for (int kq = 0; kq < 2; ++kq) {
                bf16x8 wh = *reinterpret_cast<const bf16x8*>(
                    LWh + erow * WPITCH + kq * 64 + lq * 16);
                bf16x8 wl_ = *reinterpret_cast<const bf16x8*>(
                    LWl + erow * WPITCH + kq * 64 + lq * 16);
                acc[lt] = __builtin_amdgcn_mfma_f32_16x16x32_bf16(wh,  xh[kq], acc[lt], 0, 0, 0);
                acc[lt] = __builtin_amdgcn_mfma_f32_16x16x32_bf16(wl_, xh[kq], acc[lt], 0, 0, 0);
                acc[lt] = __builtin_amdgcn_mfma_f32_16x16x32_bf16(wh,  xl[kq], acc[lt], 0, 0, 0);
            }
        }
    }

    // epilogue: C rows = e (lt*16+lq*4+r), col = l (fixed per lane)
    if (pid < 2) {
        unsigned short* Oh_ = (pid == 0) ? Qh : Kh;
        unsigned short* Ol_ = (pid == 0) ? Ql : Kl;
        size_t rowbase = ((size_t)m * Lq + l0 + wl) * 64;
        #pragma unroll
        for (int lt = 0; lt < 4; ++lt) {
            union { unsigned short u[4]; uint2 v2; } hp, lp;
            #pragma unroll
            for (int r = 0; r < 4; ++r) {
                float y = acc[lt][r];
                hp.u[r] = f2bf(y);
                lp.u[r] = f2bf(y - bfbits2f(hp.u[r]));
            }
            *reinterpret_cast<uint2*>(Oh_ + rowbase + lt * 16 + lq * 4) = hp.v2;
            *reinterpret_cast<uint2*>(Ol_ + rowbase + lt * 16 + lq * 4) = lp.v2;
        }
    } else {
        #pragma unroll
        for (int lt = 0; lt < 4; ++lt)
            #pragma unroll
            for (int r = 0; r < 4; ++r) {
                int dd = lt * 16 + lq * 4 + r;
                Vt[(((size_t)(m * 64 + dd)) << 10) + l0 + wl] = f2bf(acc[lt][r]);
            }
    }
}

// ---------------------------------------------------------------------------
// Kernel 2: MFMA fused attention (unchanged from R5 except O epilogue:
// O now written NATURAL [m][l][dd] with direct stores, feeding MFMA oproj).
// ---------------------------------------------------------------------------
__device__ __forceinline__ void stage_tile64(
    unsigned char* dst, const unsigned short* __restrict__ src,
    size_t row_stride, int tid)
{
    #pragma unroll
    for (int q = 0; q < 2; ++q) {
        int u = tid + q * 256;              // 512 units of 16B
        int row = u >> 3, off = u & 7;
        uint4 d = *reinterpret_cast<const uint4*>(src + (size_t)row * row_stride + off * 8);
        *reinterpret_cast<uint4*>(dst + ((row * 128 + off * 16) ^ ((row & 7) << 4))) = d;
    }
}

__global__ __launch_bounds__(256) void fused_attn_kernel(
    const unsigned short* __restrict__ Qh, const unsigned short* __restrict__ Ql,
    const unsigned short* __restrict__ Kh, const unsigned short* __restrict__ Kl,
    const unsigned short* __restrict__ Vt, float* __restrict__ attn_out,
    unsigned short* __restrict__ Ot)
{
    __shared__ float4 ldsf4[2128];   // 34048 B
    unsigned char* L   = (unsigned char*)ldsf4;
    unsigned char* Lkh = L;            // 8 KiB  K-hi [s][dd]
    unsigned char* Lkl = L + 8192;     // 8 KiB  K-lo
    unsigned char* Lvt = L + 16384;    // 8 KiB  V^T [dd][s]
    unsigned char* Lp  = L + 24576;    // 8 KiB  P bf16 [l][s]
    float* rowsumW = (float*)(L + 32768);   // [4][64]
    float* invrow  = (float*)(L + 33792);   // [64]

    const int fid = blockIdx.y * gridDim.x + blockIdx.x;
    const int nid = (fid & 7) * 192 + (fid >> 3);
    const int m  = nid >> 4;
    const int l0 = (nid & 15) * 64;

    const int tid = threadIdx.x;
    const int w    = tid >> 6;
    const int ln   = tid & 63;
    const int ln15 = ln & 15;
    const int lq   = ln >> 4;
    const int sc   = w * 16;          // this wave's s-columns (QK)

    // ---- preload Q fragments (hi+lo) into registers via LDS bounce ----
    stage_tile64(Lkh, Qh + ((size_t)m * Lq + l0) * 64, 64, tid);
    stage_tile64(Lkl, Ql + ((size_t)m * Lq + l0) * 64, 64, tid);
    __syncthreads();
    bf16x8 qfh[4][2], qfl[4][2];
    #pragma unroll
    for (int lt = 0; lt < 4; ++lt) {
        int row = lt * 16 + ln15;
        #pragma unroll
        for (int kq = 0; kq < 2; ++kq) {
            int byte = (row * 128 + kq * 64 + lq * 16) ^ ((row & 7) << 4);
            qfh[lt][kq] = *reinterpret_cast<const bf16x8*>(Lkh + byte);
            qfl[lt][kq] = *reinterpret_cast<const bf16x8*>(Lkl + byte);
        }
    }
    __syncthreads();

    const size_t mbase = (size_t)m * Lq * Lq;
    const unsigned short* Khm = Kh + (size_t)m * Lq * 64;
    const unsigned short* Klm = Kl + (size_t)m * Lq * 64;
    const unsigned short* Vtm = Vt + (((size_t)m * 64) << 10);

    // ================= pass 1: row sums =================
    float lsum[4][4] = {};
    for (int s0 = 0; s0 < Lq; s0 += 64) {
        stage_tile64(Lkh, Khm + (size_t)s0 * 64, 64, tid);
        stage_tile64(Lkl, Klm + (size_t)s0 * 64, 64, tid);
        __syncthreads();
        bf16x8 bh[2], bl[2];
        #pragma unroll
        for (int kq = 0; kq < 2; ++kq) {
            int row = sc + ln15;
            int byte = (row * 128 + kq * 64 + lq * 16) ^ ((row & 7) << 4);
            bh[kq] = *reinterpret_cast<const bf16x8*>(Lkh + byte);
            bl[kq] = *reinterpret_cast<const bf16x8*>(Lkl + byte);
        }
        #pragma unroll
        for (int lt = 0; lt < 4; ++lt) {
            f32x4 c = (f32x4)0.f;
            #pragma unroll
            for (int kq = 0; kq < 2; ++kq) {
                c = __builtin_amdgcn_mfma_f32_16x16x32_bf16(qfh[lt][kq], bh[kq], c, 0, 0, 0);
                c = __builtin_amdgcn_mfma_f32_16x16x32_bf16(qfl[lt][kq], bh[kq], c, 0, 0, 0);
                c = __builtin_amdgcn_mfma_f32_16x16x32_bf16(qfh[lt][kq], bl[kq], c, 0, 0, 0);
            }
            #pragma unroll
            for (int r = 0; r < 4; ++r)
                lsum[lt][r] += __expf(c[r] * SCALE);
        }
        __syncthreads();
    }
    #pragma unroll
    for (int lt = 0; lt < 4; ++lt)
        #pragma unroll
        for (int r = 0; r < 4; ++r) {
            float vv = lsum[lt][r];
            vv += __shfl_xor(vv, 1);
            vv += __shfl_xor(vv, 2);
            vv += __shfl_xor(vv, 4);
            vv += __shfl_xor(vv, 8);
            if (ln15 == 0) rowsumW[w * 64 + lt * 16 + lq * 4 + r] = vv;
        }
    __syncthreads();
    if (tid < 64)
        invrow[tid] = 1.0f / (rowsumW[tid] + rowsumW[64 + tid] +
                              rowsumW[128 + tid] + rowsumW[192 + tid]);
    __syncthreads();

    // ================= pass 2: attn write + PV =================
    f32x4 o[4];
    o[0] = (f32x4)0.f; o[1] = (f32x4)0.f; o[2] = (f32x4)0.f; o[3] = (f32x4)0.f;

    for (int s0 = 0; s0 < Lq; s0 += 64) {
        stage_tile64(Lkh, Khm + (size_t)s0 * 64, 64, tid);
        stage_tile64(Lkl, Klm + (size_t)s0 * 64, 64, tid);
        stage_tile64(Lvt, Vtm + s0, 1024, tid);
        __syncthreads();
        bf16x8 bh[2], bl[2];
        #pragma unroll
        for (int kq = 0; kq < 2; ++kq) {
            int row = sc + ln15;
            int byte = (row * 128 + kq * 64 + lq * 16) ^ ((row & 7) << 4);
            bh[kq] = *reinterpret_cast<const bf16x8*>(Lkh + byte);
            bl[kq] = *reinterpret_cast<const bf16x8*>(Lkl + byte);
        }
        #pragma unroll
        for (int lt = 0; lt < 4; ++lt) {
            f32x4 c = (f32x4)0.f;
            #pragma unroll
            for (int kq = 0; kq < 2; ++kq) {
                c = __builtin_amdgcn_mfma_f32_16x16x32_bf16(qfh[lt][kq], bh[kq], c, 0, 0, 0);
                c = __builtin_amdgcn_mfma_f32_16x16x32_bf16(qfl[lt][kq], bh[kq], c, 0, 0, 0);
                c = __builtin_amdgcn_mfma_f32_16x16x32_bf16(qfh[lt][kq], bl[kq], c, 0, 0, 0);
            }
            #pragma unroll
            for (int r = 0; r < 4; ++r) {
                int l = lt * 16 + lq * 4 + r;
                float p = __expf(c[r] * SCALE) * invrow[l];
                attn_out[mbase + (size_t)(l0 + l) * Lq + s0 + sc + ln15] = p;
                int byte = (l * 128 + (sc + ln15) * 2) ^ ((l & 7) << 4);
                *reinterpret_cast<unsigned short*>(Lp + byte) = f2bf(p);
            }
        }
        __syncthreads();   // P visible to all waves
        {
            int prow = w * 16 + ln15;   // PV A rows: this wave's l-strip
            #pragma unroll
            for (int kq = 0; kq < 2; ++kq) {
                bf16x8 pa = *reinterpret_cast<const bf16x8*>(
                    Lp + ((prow * 128 + kq * 64 + lq * 16) ^ ((prow & 7) << 4)));
                #pragma unroll
                for (int nt = 0; nt < 4; ++nt) {
                    int vrow = nt * 16 + ln15;
                    bf16x8 vb = *reinterpret_cast<const bf16x8*>(
                        Lvt + ((vrow * 128 + kq * 64 + lq * 16) ^ ((vrow & 7) << 4)));
                    o[nt] = __builtin_amdgcn_mfma_f32_16x16x32_bf16(pa, vb, o[nt], 0, 0, 0);
                }
            }
        }
        __syncthreads();   // PV reads done; safe to restage
    }

    // ---- O epilogue: direct stores, NATURAL [m][l][dd] ----
    #pragma unroll
    for (int nt = 0; nt < 4; ++nt) {
        int dd = nt * 16 + ln15;
        #pragma unroll
        for (int r = 0; r < 4; ++r) {
            int l = w * 16 + lq * 4 + r;
            Ot[((size_t)m * Lq + l0 + l) * 64 + dd] = f2bf(o[nt][r]);
        }
    }
}

// ---------------------------------------------------------------------------
// Kernel 3: MFMA output projection.
// out[b,e,v,l] = sum_{h,dd} Wo[e][h*64+dd] * O[m(b,h,v)][l][dd].
// A = Wo split hi/lo (2-term, LDS 144B pitch); B = O bf16 natural (one 16B
// global load per frag). C: row = e, col = l.
// block 256 (4 waves strip l), tile 64e x 64l, K-tile = one head (64).
// grid (16,8,12) = 1536 blocks, chunk-swizzled (1536 = 8*192).
// ---------------------------------------------------------------------------
__global__ __launch_bounds__(256, 4) void oproj_kernel(
    const float* __restrict__ Wo, const unsigned short* __restrict__ Ot,
    float* __restrict__ out)
{
    __shared__ unsigned char Wlds[2 * 64 * WPITCH];
    unsigned char* LWh = Wlds;
    unsigned char* LWl = Wlds + 64 * WPITCH;

    const int fid = (blockIdx.z * gridDim.y + blockIdx.y) * gridDim.x + blockIdx.x;
    const int nid = (fid & 7) * 192 + (fid >> 3);
    const int x_  = nid & 15;
    const int y_  = (nid >> 4) & 7;
    const int pl  = nid >> 7;
    const int b   = pl / V3;
    const int v   = pl % V3;

    const int l0 = x_ * 64;
    const int e0 = y_ * 64;

    const int tid  = threadIdx.x;
    const int w    = tid >> 6;
    const int ln   = tid & 63;
    const int ln15 = ln & 15;
    const int lq   = ln >> 4;
    const int wl   = w * 16 + ln15;

    f32x4 acc[4];
    #pragma unroll
    for (int i = 0; i < 4; ++i) acc[i] = (f32x4)0.f;

    for (int h = 0; h < Hh; ++h) {
        const int m = (b * Hh + h) * V3 + v;

        // B frags: O natural [m][l][dd] -> one uint4 per kq
        size_t obase = ((size_t)m * Lq + l0 + wl) * 64;
        bf16x8 ob0 = *reinterpret_cast<const bf16x8*>(Ot + obase + lq * 8);
        bf16x8 ob1 = *reinterpret_cast<const bf16x8*>(Ot + obase + 32 + lq * 8);

        __syncthreads();
        // stage Wo tile [64e][64d] hi/lo
        #pragma unroll
        for (int q2 = 0; q2 < 4; ++q2) {
            int idx  = tid + q2 * 256;
            int row  = idx >> 4;
            int dloc = (idx & 15) * 4;
            float4 wv4 = *reinterpret_cast<const float4*>(
                Wo + (size_t)(e0 + row) * Dm + h * 64 + dloc);
            float wz[4] = {wv4.x, wv4.y, wv4.z, wv4.w};
            union { unsigned short u[4]; uint2 v2; } hp, lp;
            #pragma unroll
            for (int e = 0; e < 4; ++e) {
                hp.u[e] = f2bf(wz[e]);
                lp.u[e] = f2bf(wz[e] - bfbits2f(hp.u[e]));
            }
            *reinterpret_cast<uint2*>(LWh + row * WPITCH + dloc * 2) = hp.v2;
            *reinterpret_cast<uint2*>(LWl + row * WPITCH + dloc * 2) = lp.v2;
        }
        __syncthreads();

        #pragma unroll
        for (int lt = 0; lt < 4; ++lt) {
            int erow = lt * 16 + ln15;
            #pragma unroll
            for (int kq = 0; kq < 2; ++kq) {
                bf16x8 wh = *reinterpret_cast<const bf16x8*>(
                    LWh + erow * WPITCH + kq * 64 + lq * 16);
                bf16x8 wl_ = *reinterpret_cast<const bf16x8*>(
                    LWl + erow * WPITCH + kq * 64 + lq * 16);
                bf16x8 ob = kq ? ob1 : ob0;
                acc[lt] = __builtin_amdgcn_mfma_f32_16x16x32_bf16(wh,  ob, acc[lt], 0, 0, 0);
                acc[lt] = __builtin_amdgcn_mfma_f32_16x16x32_bf16(wl_, ob, acc[lt], 0, 0, 0);
            }
        }
    }

    // epilogue: scalar fp32 stores (64B runs over ln15)
    #pragma unroll
    for (int lt = 0; lt < 4; ++lt)
        #pragma unroll
        for (int r = 0; r < 4; ++r) {
            int e = e0 + lt * 16 + lq * 4 + r;
            out[((size_t)(b * Dm + e) * V3 + v) * Lq + l0 + wl] = acc[lt][r];
        }
}

// ---------------------------------------------------------------------------
extern "C" void kernel_launch(void* const* d_in, const int* in_sizes, int n_in,
                              void* d_out, int out_size, void* d_ws, size_t ws_size,
                              hipStream_t stream)
{
    const float* q  = (const float*)d_in[0];
    const float* k  = (const float*)d_in[1];
    const float* vv = (const float*)d_in[2];
    const float* Wq = (const float*)d_in[3];
    const float* Wk = (const float*)d_in[4];
    const float* Wv = (const float*)d_in[5];
    const float* Wo = (const float*)d_in[6];

    float* out      = (float*)d_out;
    float* attn_out = out + (size_t)Bn * Dm * V3 * Lq;   // 6,291,456 elems in

    // workspace layout (bytes), each buffer 12,582,912 B (bf16 [96][1024][64]):
    //   Qh 0 | Ql 12582912 | Kh 25165824 | Kl 37748736 | Vt 50331648 | Ot 62914560
    char* w = (char*)d_ws;
    unsigned short* Qh = (unsigned short*)(w);
    unsigned short* Ql = (unsigned short*)(w + 12582912);
    unsigned short* Kh = (unsigned short*)(w + 25165824);
    unsigned short* Kl = (unsigned short*)(w + 37748736);
    unsigned short* Vt = (unsigned short*)(w + 50331648);
    unsigned short* Ot = (unsigned short*)(w + 62914560);

    dim3 b256(256);

    proj_all_kernel<<<dim3(16, 8, 36), b256, 0, stream>>>(
        q, k, vv, Wq, Wk, Wv, Qh, Ql, Kh, Kl, Vt);

    fused_attn_kernel<<<dim3(16, NM), b256, 0, stream>>>(
        Qh, Ql, Kh, Kl, Vt, attn_out, Ot);

    oproj_kernel<<<dim3(16, 8, 12), b256, 0, stream>>>(Wo, Ot, out);
}